// Round 14
// baseline (216.493 us; speedup 1.0000x reference)
//
#include <hip/hip_runtime.h>
#include <hip/hip_bf16.h>
#include <math.h>

#define NN 50000
#define NE 600000
#define HD 128
#define NL 3
#define NBLK 49        // ceil(NN/1024)
#define CNT_BLKS 2344  // ceil(NE/256)
#define TW_BLKS 64     // 64*256*4 = 65536 = 4*128*128
#define GB 782         // gemm blocks (BM=64)
#define ZERO_OFF (NN << 8)   // byte offset of zero pad row mh[NN]

typedef __attribute__((ext_vector_type(8))) short short8;
typedef __attribute__((ext_vector_type(4))) float f32x4;

__device__ __forceinline__ ushort f2bf(float v) {
    union { float f; unsigned u; } c; c.f = v;
    unsigned u = c.u;
    u = (u + 0x7fffu + ((u >> 16) & 1u)) >> 16;
    return (ushort)u;
}
__device__ __forceinline__ float u2f(uint u) {
    union { uint u; float f; } c; c.u = u; return c.f;
}

// ---------- K1: zero deg (blocks [0,NBLK)) + W transpose (blocks rest) -------
__global__ __launch_bounds__(256) void init_k(int* __restrict__ deg,
                                              const float* __restrict__ W_in,
                                              const float* __restrict__ W_layers,
                                              ushort* __restrict__ WT) {
    int b = blockIdx.x;
    if (b < NBLK) {
        int base = b * 1024 + threadIdx.x * 4;
        if (base + 4 <= NN) {
            *(int4*)(deg + base) = int4{0, 0, 0, 0};
        } else {
            for (int u = 0; u < 4; ++u) if (base + u < NN) deg[base + u] = 0;
        }
    } else {
        int tloc = (b - NBLK) * 256 + threadIdx.x; // 0..16383
        #pragma unroll
        for (int q = 0; q < 4; ++q) {
            int idx = tloc + q * 16384;
            int m = idx >> 14;
            int c = (idx >> 7) & 127;
            int k = idx & 127;
            const float* W = (m == 0) ? W_in : (W_layers + (size_t)(m - 1) * HD * HD);
            WT[idx] = f2bf(W[k * HD + c]);
        }
    }
}

// ---------- scan phase 1: block-local exclusive scan + block totals ----------
__global__ __launch_bounds__(1024) void scan_partial_k(const int* __restrict__ deg,
                                                       int* __restrict__ rowptr,
                                                       int* __restrict__ partial) {
    __shared__ int wsum[16];
    int tid = threadIdx.x;
    int lane = tid & 63, w = tid >> 6;
    int v = blockIdx.x * 1024 + tid;
    int x = (v < NN) ? deg[v] : 0;
    int s = x;
    #pragma unroll
    for (int off = 1; off < 64; off <<= 1) {
        int t = __shfl_up(s, off);
        if (lane >= off) s += t;
    }
    if (lane == 63) wsum[w] = s;
    __syncthreads();
    if (w == 0) {
        int t = (lane < 16) ? wsum[lane] : 0;
        #pragma unroll
        for (int off = 1; off < 16; off <<= 1) {
            int u = __shfl_up(t, off);
            if (lane >= off) t += u;
        }
        if (lane < 16) wsum[lane] = t;
    }
    __syncthreads();
    int incl = s + ((w > 0) ? wsum[w - 1] : 0);
    if (v < NN) rowptr[v] = incl - x;
    if (tid == 1023) partial[blockIdx.x] = incl;
}

// ---------- scan phase 2 (fused): redundant 49-scan per block + finalize -----
__global__ __launch_bounds__(1024) void add_off_isq_k(const int* __restrict__ deg,
                                                      int* __restrict__ rowptr,
                                                      const int* __restrict__ partial,
                                                      int* __restrict__ cursor,
                                                      float* __restrict__ isq,
                                                      ushort* __restrict__ mh) {
    __shared__ int spart[NBLK + 1];
    int tid = threadIdx.x;
    if (tid < 64) {
        int xval = (tid < NBLK) ? partial[tid] : 0;
        int s = xval;
        #pragma unroll
        for (int off = 1; off < 64; off <<= 1) {
            int t = __shfl_up(s, off);
            if (tid >= off) s += t;
        }
        if (tid < NBLK) spart[tid] = s - xval;   // exclusive
        if (tid == NBLK - 1) spart[NBLK] = s;    // grand total
    }
    __syncthreads();
    int v = blockIdx.x * 1024 + tid;
    if (v < NN) {
        int rv = rowptr[v] + spart[blockIdx.x];
        rowptr[v] = rv;
        cursor[v] = rv;
        isq[v] = rsqrtf((float)(deg[v] + 1));
    }
    if (blockIdx.x == 0 && tid == 0) rowptr[NN] = spart[NBLK];
    // zero the pad row mh[NN] (256 B)
    if (blockIdx.x == 0 && tid < 64)
        ((uint*)(mh + (size_t)NN * HD))[tid] = 0u;
}

// ---------------- GEMM body: out = A[nrows,128] @ W[128,128] -----------------
// BM=64, 4 waves, each wave owns 16 rows x 128 cols.
// MODE 0: A f32 (x).  h[r][c] = acc + bias[c];  hb = bf16(h)
// MODE 1: A bf16 (hb). mh[r][c] = bf16(acc * isq[r])
template<int MODE>
__device__ __forceinline__ void gemm_body(int bid, const void* __restrict__ Av,
                                          const ushort* __restrict__ WT,
                                          const float* __restrict__ bs,
                                          float* __restrict__ out_f32,
                                          ushort* __restrict__ out_b16,
                                          int nrows, ushort* swT) {
    int tid = threadIdx.x;
    #pragma unroll
    for (int i = 0; i < 8; ++i) {
        int chunk = tid + i * 256;
        int lin = chunk << 4;
        int n = lin >> 8;
        int swz = lin ^ ((n & 7) << 4);
        *(float4*)((char*)swT + swz) = *(const float4*)(WT + chunk * 8);
    }
    __syncthreads();

    int w = tid >> 6, l = tid & 63;
    int ar = l & 15, ag = l >> 4;
    int r0 = bid * 64 + w * 16;
    int arow = r0 + ar;
    bool arow_ok = arow < nrows;

    short8 afr[4];
    #pragma unroll
    for (int ks = 0; ks < 4; ++ks) {
        if (MODE == 0) {
            short8 fr = {0,0,0,0,0,0,0,0};
            if (arow_ok) {
                const float* Af = (const float*)Av;
                float4 p0 = *(const float4*)(Af + (size_t)arow * HD + ks * 32 + ag * 8);
                float4 p1 = *(const float4*)(Af + (size_t)arow * HD + ks * 32 + ag * 8 + 4);
                fr[0] = (short)f2bf(p0.x); fr[1] = (short)f2bf(p0.y);
                fr[2] = (short)f2bf(p0.z); fr[3] = (short)f2bf(p0.w);
                fr[4] = (short)f2bf(p1.x); fr[5] = (short)f2bf(p1.y);
                fr[6] = (short)f2bf(p1.z); fr[7] = (short)f2bf(p1.w);
            }
            afr[ks] = fr;
        } else {
            const ushort* Ab = (const ushort*)Av;
            afr[ks] = arow_ok ? *(const short8*)(Ab + (size_t)arow * HD + ks * 32 + ag * 8)
                              : short8{0,0,0,0,0,0,0,0};
        }
    }

    f32x4 acc[8];
    #pragma unroll
    for (int t = 0; t < 8; ++t) acc[t] = f32x4{0.f, 0.f, 0.f, 0.f};

    #pragma unroll
    for (int ks = 0; ks < 4; ++ks) {
        #pragma unroll
        for (int t = 0; t < 8; ++t) {
            int n = t * 16 + ar;
            int lin = (n << 8) + ks * 64 + ag * 16;
            int swz = lin ^ ((ar & 7) << 4);
            short8 b = *(const short8*)((const char*)swT + swz);
            acc[t] = __builtin_amdgcn_mfma_f32_16x16x32_bf16(afr[ks], b, acc[t], 0, 0, 0);
        }
    }

    #pragma unroll
    for (int q = 0; q < 4; ++q) {
        int row = r0 + ag * 4 + q;
        if (row >= nrows) continue;
        if (MODE == 0) {
            #pragma unroll
            for (int t = 0; t < 8; ++t) {
                int col = t * 16 + ar;
                float v = acc[t][q] + bs[col];
                out_f32[(size_t)row * HD + col] = v;
                out_b16[(size_t)row * HD + col] = f2bf(v);
            }
        } else {
            float s = bs[row];
            #pragma unroll
            for (int t = 0; t < 8; ++t) {
                int col = t * 16 + ar;
                out_b16[(size_t)row * HD + col] = f2bf(acc[t][q] * s);
            }
        }
    }
}

// ---------- K2: gemm0 (blocks [0,GB)) + count_deg (blocks rest) --------------
__global__ __launch_bounds__(256) void gemm0_deg_k(const float* __restrict__ x,
                                                   const ushort* __restrict__ WT,
                                                   const float* __restrict__ b_in,
                                                   float* __restrict__ h,
                                                   ushort* __restrict__ hb,
                                                   const int* __restrict__ dst,
                                                   int* __restrict__ deg) {
    __shared__ ushort swT[HD * HD];
    int b = blockIdx.x;
    if (b < GB) {
        gemm_body<0>(b, x, WT, b_in, h, hb, NN, swT);
    } else {
        int e = (b - GB) * 256 + threadIdx.x;
        if (e < NE) atomicAdd(&deg[dst[e]], 1);
    }
}

// ---------- K5: gemm1 (blocks [0,GB)) + csr_fill (blocks rest) ---------------
__global__ __launch_bounds__(256) void gemm1_csr_k(const ushort* __restrict__ hb,
                                                   const ushort* __restrict__ WT1,
                                                   const float* __restrict__ isq,
                                                   ushort* __restrict__ mh,
                                                   const int* __restrict__ src,
                                                   const int* __restrict__ dst,
                                                   int* __restrict__ cursor,
                                                   int* __restrict__ csrb) {
    __shared__ ushort swT[HD * HD];
    int b = blockIdx.x;
    if (b < GB) {
        gemm_body<1>(b, hb, WT1, isq, nullptr, mh, NN, swT);
    } else {
        int e = (b - GB) * 256 + threadIdx.x;
        if (e < NE) {
            int pos = atomicAdd(&cursor[dst[e]], 1);
            csrb[pos] = src[e] << 8; // row byte offset (HD*2 = 256 B)
        }
    }
}

// ---------- plain gemm kernel for layers 1,2 ---------------------------------
__global__ __launch_bounds__(256) void gemm_mfma_k(const ushort* __restrict__ A,
                                                   const ushort* __restrict__ WT,
                                                   const float* __restrict__ isq,
                                                   ushort* __restrict__ mh) {
    __shared__ ushort swT[HD * HD];
    gemm_body<1>(blockIdx.x, A, WT, isq, nullptr, mh, NN, swT);
}

// ------- aggregation: one wave/node, flat-16 unpredicated batches (depth-1) --
// h[v] = gelu( isq[v]*(sum_in mh[src] + mh[v]) + b ) + h[v];  hb = bf16(h)
template<int WRITE_HB>
__global__ __launch_bounds__(256) void aggregate_k(const ushort* __restrict__ mh,
                                                   const int* __restrict__ rowptr,
                                                   const int* __restrict__ csrb,
                                                   const float* __restrict__ isq,
                                                   const float* __restrict__ bias,
                                                   float* __restrict__ h,
                                                   ushort* __restrict__ hb) {
    int gw = (int)((blockIdx.x * blockDim.x + threadIdx.x) >> 6);
    int lane = threadIdx.x & 63;
    if (gw >= NN) return;
    int v = gw;
    int2 rp = *(const int2*)&rowptr[v];
    const char* mh_lane = (const char*)mh + lane * 4; // this lane's 2 channels

    // self-loop init
    uint sp = *(const uint*)(mh_lane + ((size_t)v << 8));
    float accx = u2f(sp << 16), accy = u2f(sp & 0xffff0000u);

    for (int i = rp.x; i < rp.y; i += 64) {
        int offs = (i + lane < rp.y) ? csrb[i + lane] : ZERO_OFF;
        int cnt = min(64, rp.y - i);
        int nb = (cnt + 15) >> 4;          // 1..4 batches of 16 (pads -> zero row)
        for (int b = 0; b < nb; ++b) {
            int jb = b << 4;
            int o0  = __shfl(offs, jb);
            int o1  = __shfl(offs, jb + 1);
            int o2  = __shfl(offs, jb + 2);
            int o3  = __shfl(offs, jb + 3);
            int o4  = __shfl(offs, jb + 4);
            int o5  = __shfl(offs, jb + 5);
            int o6  = __shfl(offs, jb + 6);
            int o7  = __shfl(offs, jb + 7);
            int o8  = __shfl(offs, jb + 8);
            int o9  = __shfl(offs, jb + 9);
            int o10 = __shfl(offs, jb + 10);
            int o11 = __shfl(offs, jb + 11);
            int o12 = __shfl(offs, jb + 12);
            int o13 = __shfl(offs, jb + 13);
            int o14 = __shfl(offs, jb + 14);
            int o15 = __shfl(offs, jb + 15);
            uint p0  = *(const uint*)(mh_lane + o0);
            uint p1  = *(const uint*)(mh_lane + o1);
            uint p2  = *(const uint*)(mh_lane + o2);
            uint p3  = *(const uint*)(mh_lane + o3);
            uint p4  = *(const uint*)(mh_lane + o4);
            uint p5  = *(const uint*)(mh_lane + o5);
            uint p6  = *(const uint*)(mh_lane + o6);
            uint p7  = *(const uint*)(mh_lane + o7);
            uint p8  = *(const uint*)(mh_lane + o8);
            uint p9  = *(const uint*)(mh_lane + o9);
            uint p10 = *(const uint*)(mh_lane + o10);
            uint p11 = *(const uint*)(mh_lane + o11);
            uint p12 = *(const uint*)(mh_lane + o12);
            uint p13 = *(const uint*)(mh_lane + o13);
            uint p14 = *(const uint*)(mh_lane + o14);
            uint p15 = *(const uint*)(mh_lane + o15);
            accx += u2f(p0 << 16);  accy += u2f(p0 & 0xffff0000u);
            accx += u2f(p1 << 16);  accy += u2f(p1 & 0xffff0000u);
            accx += u2f(p2 << 16);  accy += u2f(p2 & 0xffff0000u);
            accx += u2f(p3 << 16);  accy += u2f(p3 & 0xffff0000u);
            accx += u2f(p4 << 16);  accy += u2f(p4 & 0xffff0000u);
            accx += u2f(p5 << 16);  accy += u2f(p5 & 0xffff0000u);
            accx += u2f(p6 << 16);  accy += u2f(p6 & 0xffff0000u);
            accx += u2f(p7 << 16);  accy += u2f(p7 & 0xffff0000u);
            accx += u2f(p8 << 16);  accy += u2f(p8 & 0xffff0000u);
            accx += u2f(p9 << 16);  accy += u2f(p9 & 0xffff0000u);
            accx += u2f(p10 << 16); accy += u2f(p10 & 0xffff0000u);
            accx += u2f(p11 << 16); accy += u2f(p11 & 0xffff0000u);
            accx += u2f(p12 << 16); accy += u2f(p12 & 0xffff0000u);
            accx += u2f(p13 << 16); accy += u2f(p13 & 0xffff0000u);
            accx += u2f(p14 << 16); accy += u2f(p14 & 0xffff0000u);
            accx += u2f(p15 << 16); accy += u2f(p15 & 0xffff0000u);
        }
    }

    float is = isq[v];
    float2 b = *(const float2*)&bias[lane * 2];
    float ax = accx * is + b.x;
    float ay = accy * is + b.y;
    float gx = 0.5f * ax * (1.f + erff(ax * 0.70710678118654752f));
    float gy = 0.5f * ay * (1.f + erff(ay * 0.70710678118654752f));
    float* hp = h + (size_t)v * HD + lane * 2;
    float2 hv = *(const float2*)hp;
    hv.x += gx; hv.y += gy;
    *(float2*)hp = hv;
    if (WRITE_HB) {
        uint packed = ((uint)f2bf(hv.x)) | (((uint)f2bf(hv.y)) << 16);
        *(uint*)((char*)hb + ((size_t)v << 8) + lane * 4) = packed;
    }
}

// ---------------- launch ----------------

static inline size_t align_up(size_t x, size_t a) { return (x + a - 1) & ~(a - 1); }

extern "C" void kernel_launch(void* const* d_in, const int* in_sizes, int n_in,
                              void* d_out, int out_size, void* d_ws, size_t ws_size,
                              hipStream_t stream) {
    const float* x        = (const float*)d_in[0];
    const int*   eidx     = (const int*)d_in[1];
    const float* W_in     = (const float*)d_in[2];
    const float* b_in     = (const float*)d_in[3];
    const float* W_layers = (const float*)d_in[4];
    const float* b_layers = (const float*)d_in[5];
    float* h = (float*)d_out;

    const int* src = eidx;
    const int* dst = eidx + NE;

    // workspace carve-up (~33 MB)
    char* p = (char*)d_ws;
    ushort* mh = (ushort*)p;      p += align_up(sizeof(ushort) * ((size_t)NN + 1) * HD, 256);
    ushort* hb = (ushort*)p;      p += align_up(sizeof(ushort) * (size_t)NN * HD, 256);
    ushort* WT = (ushort*)p;      p += align_up(sizeof(ushort) * 4 * HD * HD, 256);
    float* isq = (float*)p;       p += align_up(sizeof(float) * NN, 256);
    int* deg = (int*)p;           p += align_up(sizeof(int) * NN, 256);
    int* cursor = (int*)p;        p += align_up(sizeof(int) * NN, 256);
    int* rowptr = (int*)p;        p += align_up(sizeof(int) * (NN + 1), 256);
    int* partial = (int*)p;       p += align_up(sizeof(int) * (NBLK + 1), 256);
    int* csrb = (int*)p;          p += align_up(sizeof(int) * NE, 256);

    // K1: zero deg + transpose/convert all W
    init_k<<<NBLK + TW_BLKS, 256, 0, stream>>>(deg, W_in, W_layers, WT);
    // K2: h = x @ W_in + b_in (hb = bf16(h))  ||  count_deg
    gemm0_deg_k<<<GB + CNT_BLKS, 256, 0, stream>>>(x, WT, b_in, h, hb, dst, deg);
    // K3/K4: scan deg -> rowptr; cursor/isq/pad
    scan_partial_k<<<NBLK, 1024, 0, stream>>>(deg, rowptr, partial);
    add_off_isq_k<<<NBLK, 1024, 0, stream>>>(deg, rowptr, partial, cursor, isq, mh);
    // K5: mh = bf16((hb @ W_0) * isq)  ||  csr_fill
    gemm1_csr_k<<<GB + CNT_BLKS, 256, 0, stream>>>(hb, WT + (size_t)HD * HD, isq, mh,
                                                   src, dst, cursor, csrb);

    for (int l = 0; l < NL; ++l) {
        if (l > 0) {
            // mh = bf16((hb @ W_l) * isq)
            gemm_mfma_k<<<GB, 256, 0, stream>>>(hb, WT + (size_t)(l + 1) * HD * HD,
                                                isq, mh);
        }
        // h = gelu(isq*(sum mh[src] + mh[v]) + b_l) + h ; hb = bf16(h) except last
        if (l < NL - 1)
            aggregate_k<1><<<(NN + 3) / 4, 256, 0, stream>>>(mh, rowptr, csrb, isq,
                                                             b_layers + (size_t)l * HD, h, hb);
        else
            aggregate_k<0><<<(NN + 3) / 4, 256, 0, stream>>>(mh, rowptr, csrb, isq,
                                                             b_layers + (size_t)l * HD, h, hb);
    }
}

// Round 15
// 204.772 us; speedup vs baseline: 1.0572x; 1.0572x over previous
//
#include <hip/hip_runtime.h>
#include <hip/hip_bf16.h>
#include <math.h>

#define NN 50000
#define NE 600000
#define HD 128
#define NL 3
#define NBLK 49        // ceil(NN/1024)
#define TW_BLKS 64     // 64*256*4 = 65536 = 4*128*128
#define GB 782         // gemm blocks (BM=64)
#define NCHUNK 256     // edge chunks per residue
#define CHK 2344       // ceil(NE/NCHUNK)
#define FIL_BLKS (8 * NCHUNK)  // 2048 partner blocks (8 residues x 256 chunks)
#define DRANGE 6250    // NN/8 dst's per XCD residue
#define ZERO_OFF (NN << 8)   // byte offset of zero pad row mh[NN]

typedef __attribute__((ext_vector_type(8))) short short8;
typedef __attribute__((ext_vector_type(4))) float f32x4;

__device__ __forceinline__ ushort f2bf(float v) {
    union { float f; unsigned u; } c; c.f = v;
    unsigned u = c.u;
    u = (u + 0x7fffu + ((u >> 16) & 1u)) >> 16;
    return (ushort)u;
}
__device__ __forceinline__ float u2f(uint u) {
    union { uint u; float f; } c; c.u = u; return c.f;
}

// ---------- K1: zero deg (blocks [0,NBLK)) + W transpose (blocks rest) -------
__global__ __launch_bounds__(256) void init_k(int* __restrict__ deg,
                                              const float* __restrict__ W_in,
                                              const float* __restrict__ W_layers,
                                              ushort* __restrict__ WT) {
    int b = blockIdx.x;
    if (b < NBLK) {
        int base = b * 1024 + threadIdx.x * 4;
        if (base + 4 <= NN) {
            *(int4*)(deg + base) = int4{0, 0, 0, 0};
        } else {
            for (int u = 0; u < 4; ++u) if (base + u < NN) deg[base + u] = 0;
        }
    } else {
        int tloc = (b - NBLK) * 256 + threadIdx.x; // 0..16383
        #pragma unroll
        for (int q = 0; q < 4; ++q) {
            int idx = tloc + q * 16384;
            int m = idx >> 14;
            int c = (idx >> 7) & 127;
            int k = idx & 127;
            const float* W = (m == 0) ? W_in : (W_layers + (size_t)(m - 1) * HD * HD);
            WT[idx] = f2bf(W[k * HD + c]);
        }
    }
}

// ---------- scan phase 1: block-local exclusive scan + block totals ----------
__global__ __launch_bounds__(1024) void scan_partial_k(const int* __restrict__ deg,
                                                       int* __restrict__ rowptr,
                                                       int* __restrict__ partial) {
    __shared__ int wsum[16];
    int tid = threadIdx.x;
    int lane = tid & 63, w = tid >> 6;
    int v = blockIdx.x * 1024 + tid;
    int x = (v < NN) ? deg[v] : 0;
    int s = x;
    #pragma unroll
    for (int off = 1; off < 64; off <<= 1) {
        int t = __shfl_up(s, off);
        if (lane >= off) s += t;
    }
    if (lane == 63) wsum[w] = s;
    __syncthreads();
    if (w == 0) {
        int t = (lane < 16) ? wsum[lane] : 0;
        #pragma unroll
        for (int off = 1; off < 16; off <<= 1) {
            int u = __shfl_up(t, off);
            if (lane >= off) t += u;
        }
        if (lane < 16) wsum[lane] = t;
    }
    __syncthreads();
    int incl = s + ((w > 0) ? wsum[w - 1] : 0);
    if (v < NN) rowptr[v] = incl - x;
    if (tid == 1023) partial[blockIdx.x] = incl;
}

// ---------- scan phase 2 (fused): redundant 49-scan per block + finalize -----
__global__ __launch_bounds__(1024) void add_off_isq_k(const int* __restrict__ deg,
                                                      int* __restrict__ rowptr,
                                                      const int* __restrict__ partial,
                                                      int* __restrict__ cursor,
                                                      float* __restrict__ isq,
                                                      ushort* __restrict__ mh) {
    __shared__ int spart[NBLK + 1];
    int tid = threadIdx.x;
    if (tid < 64) {
        int xval = (tid < NBLK) ? partial[tid] : 0;
        int s = xval;
        #pragma unroll
        for (int off = 1; off < 64; off <<= 1) {
            int t = __shfl_up(s, off);
            if (tid >= off) s += t;
        }
        if (tid < NBLK) spart[tid] = s - xval;   // exclusive
        if (tid == NBLK - 1) spart[NBLK] = s;    // grand total
    }
    __syncthreads();
    int v = blockIdx.x * 1024 + tid;
    if (v < NN) {
        int rv = rowptr[v] + spart[blockIdx.x];
        rowptr[v] = rv;
        cursor[v] = rv;
        isq[v] = rsqrtf((float)(deg[v] + 1));
    }
    if (blockIdx.x == 0 && tid == 0) rowptr[NN] = spart[NBLK];
    // zero the pad row mh[NN] (256 B)
    if (blockIdx.x == 0 && tid < 64)
        ((uint*)(mh + (size_t)NN * HD))[tid] = 0u;
}

// ---------------- GEMM body: out = A[nrows,128] @ W[128,128] -----------------
// BM=64, 4 waves, each wave owns 16 rows x 128 cols.
// MODE 0: A f32 (x).  h[r][c] = acc + bias[c];  hb = bf16(h)
// MODE 1: A bf16 (hb). mh[r][c] = bf16(acc * isq[r])
template<int MODE>
__device__ __forceinline__ void gemm_body(int bid, const void* __restrict__ Av,
                                          const ushort* __restrict__ WT,
                                          const float* __restrict__ bs,
                                          float* __restrict__ out_f32,
                                          ushort* __restrict__ out_b16,
                                          int nrows, ushort* swT) {
    int tid = threadIdx.x;
    #pragma unroll
    for (int i = 0; i < 8; ++i) {
        int chunk = tid + i * 256;
        int lin = chunk << 4;
        int n = lin >> 8;
        int swz = lin ^ ((n & 7) << 4);
        *(float4*)((char*)swT + swz) = *(const float4*)(WT + chunk * 8);
    }
    __syncthreads();

    int w = tid >> 6, l = tid & 63;
    int ar = l & 15, ag = l >> 4;
    int r0 = bid * 64 + w * 16;
    int arow = r0 + ar;
    bool arow_ok = arow < nrows;

    short8 afr[4];
    #pragma unroll
    for (int ks = 0; ks < 4; ++ks) {
        if (MODE == 0) {
            short8 fr = {0,0,0,0,0,0,0,0};
            if (arow_ok) {
                const float* Af = (const float*)Av;
                float4 p0 = *(const float4*)(Af + (size_t)arow * HD + ks * 32 + ag * 8);
                float4 p1 = *(const float4*)(Af + (size_t)arow * HD + ks * 32 + ag * 8 + 4);
                fr[0] = (short)f2bf(p0.x); fr[1] = (short)f2bf(p0.y);
                fr[2] = (short)f2bf(p0.z); fr[3] = (short)f2bf(p0.w);
                fr[4] = (short)f2bf(p1.x); fr[5] = (short)f2bf(p1.y);
                fr[6] = (short)f2bf(p1.z); fr[7] = (short)f2bf(p1.w);
            }
            afr[ks] = fr;
        } else {
            const ushort* Ab = (const ushort*)Av;
            afr[ks] = arow_ok ? *(const short8*)(Ab + (size_t)arow * HD + ks * 32 + ag * 8)
                              : short8{0,0,0,0,0,0,0,0};
        }
    }

    f32x4 acc[8];
    #pragma unroll
    for (int t = 0; t < 8; ++t) acc[t] = f32x4{0.f, 0.f, 0.f, 0.f};

    #pragma unroll
    for (int ks = 0; ks < 4; ++ks) {
        #pragma unroll
        for (int t = 0; t < 8; ++t) {
            int n = t * 16 + ar;
            int lin = (n << 8) + ks * 64 + ag * 16;
            int swz = lin ^ ((ar & 7) << 4);
            short8 b = *(const short8*)((const char*)swT + swz);
            acc[t] = __builtin_amdgcn_mfma_f32_16x16x32_bf16(afr[ks], b, acc[t], 0, 0, 0);
        }
    }

    #pragma unroll
    for (int q = 0; q < 4; ++q) {
        int row = r0 + ag * 4 + q;
        if (row >= nrows) continue;
        if (MODE == 0) {
            #pragma unroll
            for (int t = 0; t < 8; ++t) {
                int col = t * 16 + ar;
                float v = acc[t][q] + bs[col];
                out_f32[(size_t)row * HD + col] = v;
                out_b16[(size_t)row * HD + col] = f2bf(v);
            }
        } else {
            float s = bs[row];
            #pragma unroll
            for (int t = 0; t < 8; ++t) {
                int col = t * 16 + ar;
                out_b16[(size_t)row * HD + col] = f2bf(acc[t][q] * s);
            }
        }
    }
}

// ---------- K2: gemm0 (blocks [0,GB)) + XCD-local count_deg (rest) -----------
// Partner block: residue r = bid&7 (HW round-robin -> one XCD), chunk j.
// Only edges with dst in this residue's range are counted -> deg lines stay
// in ONE XCD's L2 (no cross-XCD atomic line bouncing).
__global__ __launch_bounds__(256) void gemm0_deg_k(const float* __restrict__ x,
                                                   const ushort* __restrict__ WT,
                                                   const float* __restrict__ b_in,
                                                   float* __restrict__ h,
                                                   ushort* __restrict__ hb,
                                                   const int* __restrict__ dst,
                                                   int* __restrict__ deg) {
    __shared__ ushort swT[HD * HD];
    int b = blockIdx.x;
    if (b < GB) {
        gemm_body<0>(b, x, WT, b_in, h, hb, NN, swT);
        return;
    }
    int r = b & 7;
    int j = (b - GB) >> 3;
    int dlo = r * DRANGE, dhi = dlo + DRANGE;
    int base = j * CHK;
    int end = min(base + CHK, NE);
    for (int e = base + (int)threadIdx.x; e < end; e += 256) {
        int d = dst[e];
        if (d >= dlo && d < dhi) atomicAdd(&deg[d], 1);
    }
}

// ---------- K5: gemm1 (blocks [0,GB)) + XCD-local csr_fill (rest) ------------
__global__ __launch_bounds__(256) void gemm1_csr_k(const ushort* __restrict__ hb,
                                                   const ushort* __restrict__ WT1,
                                                   const float* __restrict__ isq,
                                                   ushort* __restrict__ mh,
                                                   const int* __restrict__ src,
                                                   const int* __restrict__ dst,
                                                   int* __restrict__ cursor,
                                                   int* __restrict__ csrb) {
    __shared__ ushort swT[HD * HD];
    int b = blockIdx.x;
    if (b < GB) {
        gemm_body<1>(b, hb, WT1, isq, nullptr, mh, NN, swT);
        return;
    }
    int r = b & 7;
    int j = (b - GB) >> 3;
    int dlo = r * DRANGE, dhi = dlo + DRANGE;
    int base = j * CHK;
    int end = min(base + CHK, NE);
    for (int e = base + (int)threadIdx.x; e < end; e += 256) {
        int d = dst[e];
        if (d >= dlo && d < dhi) {
            int pos = atomicAdd(&cursor[d], 1);   // L2-local round trip
            csrb[pos] = src[e] << 8;              // row byte offset (HD*2 = 256 B)
        }
    }
}

// ---------- plain gemm kernel for layers 1,2 ---------------------------------
__global__ __launch_bounds__(256) void gemm_mfma_k(const ushort* __restrict__ A,
                                                   const ushort* __restrict__ WT,
                                                   const float* __restrict__ isq,
                                                   ushort* __restrict__ mh) {
    __shared__ ushort swT[HD * HD];
    gemm_body<1>(blockIdx.x, A, WT, isq, nullptr, mh, NN, swT);
}

// ------- aggregation: one wave/node, flat-16 unpredicated batches (depth-1) --
// h[v] = gelu( isq[v]*(sum_in mh[src] + mh[v]) + b ) + h[v];  hb = bf16(h)
template<int WRITE_HB>
__global__ __launch_bounds__(256) void aggregate_k(const ushort* __restrict__ mh,
                                                   const int* __restrict__ rowptr,
                                                   const int* __restrict__ csrb,
                                                   const float* __restrict__ isq,
                                                   const float* __restrict__ bias,
                                                   float* __restrict__ h,
                                                   ushort* __restrict__ hb) {
    int gw = (int)((blockIdx.x * blockDim.x + threadIdx.x) >> 6);
    int lane = threadIdx.x & 63;
    if (gw >= NN) return;
    int v = gw;
    int2 rp = *(const int2*)&rowptr[v];
    const char* mh_lane = (const char*)mh + lane * 4; // this lane's 2 channels

    // self-loop init
    uint sp = *(const uint*)(mh_lane + ((size_t)v << 8));
    float accx = u2f(sp << 16), accy = u2f(sp & 0xffff0000u);

    for (int i = rp.x; i < rp.y; i += 64) {
        int offs = (i + lane < rp.y) ? csrb[i + lane] : ZERO_OFF;
        int cnt = min(64, rp.y - i);
        int nb = (cnt + 15) >> 4;          // 1..4 batches of 16 (pads -> zero row)
        for (int b = 0; b < nb; ++b) {
            int jb = b << 4;
            int o0  = __shfl(offs, jb);
            int o1  = __shfl(offs, jb + 1);
            int o2  = __shfl(offs, jb + 2);
            int o3  = __shfl(offs, jb + 3);
            int o4  = __shfl(offs, jb + 4);
            int o5  = __shfl(offs, jb + 5);
            int o6  = __shfl(offs, jb + 6);
            int o7  = __shfl(offs, jb + 7);
            int o8  = __shfl(offs, jb + 8);
            int o9  = __shfl(offs, jb + 9);
            int o10 = __shfl(offs, jb + 10);
            int o11 = __shfl(offs, jb + 11);
            int o12 = __shfl(offs, jb + 12);
            int o13 = __shfl(offs, jb + 13);
            int o14 = __shfl(offs, jb + 14);
            int o15 = __shfl(offs, jb + 15);
            uint p0  = *(const uint*)(mh_lane + o0);
            uint p1  = *(const uint*)(mh_lane + o1);
            uint p2  = *(const uint*)(mh_lane + o2);
            uint p3  = *(const uint*)(mh_lane + o3);
            uint p4  = *(const uint*)(mh_lane + o4);
            uint p5  = *(const uint*)(mh_lane + o5);
            uint p6  = *(const uint*)(mh_lane + o6);
            uint p7  = *(const uint*)(mh_lane + o7);
            uint p8  = *(const uint*)(mh_lane + o8);
            uint p9  = *(const uint*)(mh_lane + o9);
            uint p10 = *(const uint*)(mh_lane + o10);
            uint p11 = *(const uint*)(mh_lane + o11);
            uint p12 = *(const uint*)(mh_lane + o12);
            uint p13 = *(const uint*)(mh_lane + o13);
            uint p14 = *(const uint*)(mh_lane + o14);
            uint p15 = *(const uint*)(mh_lane + o15);
            accx += u2f(p0 << 16);  accy += u2f(p0 & 0xffff0000u);
            accx += u2f(p1 << 16);  accy += u2f(p1 & 0xffff0000u);
            accx += u2f(p2 << 16);  accy += u2f(p2 & 0xffff0000u);
            accx += u2f(p3 << 16);  accy += u2f(p3 & 0xffff0000u);
            accx += u2f(p4 << 16);  accy += u2f(p4 & 0xffff0000u);
            accx += u2f(p5 << 16);  accy += u2f(p5 & 0xffff0000u);
            accx += u2f(p6 << 16);  accy += u2f(p6 & 0xffff0000u);
            accx += u2f(p7 << 16);  accy += u2f(p7 & 0xffff0000u);
            accx += u2f(p8 << 16);  accy += u2f(p8 & 0xffff0000u);
            accx += u2f(p9 << 16);  accy += u2f(p9 & 0xffff0000u);
            accx += u2f(p10 << 16); accy += u2f(p10 & 0xffff0000u);
            accx += u2f(p11 << 16); accy += u2f(p11 & 0xffff0000u);
            accx += u2f(p12 << 16); accy += u2f(p12 & 0xffff0000u);
            accx += u2f(p13 << 16); accy += u2f(p13 & 0xffff0000u);
            accx += u2f(p14 << 16); accy += u2f(p14 & 0xffff0000u);
            accx += u2f(p15 << 16); accy += u2f(p15 & 0xffff0000u);
        }
    }

    float is = isq[v];
    float2 b = *(const float2*)&bias[lane * 2];
    float ax = accx * is + b.x;
    float ay = accy * is + b.y;
    float gx = 0.5f * ax * (1.f + erff(ax * 0.70710678118654752f));
    float gy = 0.5f * ay * (1.f + erff(ay * 0.70710678118654752f));
    float* hp = h + (size_t)v * HD + lane * 2;
    float2 hv = *(const float2*)hp;
    hv.x += gx; hv.y += gy;
    *(float2*)hp = hv;
    if (WRITE_HB) {
        uint packed = ((uint)f2bf(hv.x)) | (((uint)f2bf(hv.y)) << 16);
        *(uint*)((char*)hb + ((size_t)v << 8) + lane * 4) = packed;
    }
}

// ---------------- launch ----------------

static inline size_t align_up(size_t x, size_t a) { return (x + a - 1) & ~(a - 1); }

extern "C" void kernel_launch(void* const* d_in, const int* in_sizes, int n_in,
                              void* d_out, int out_size, void* d_ws, size_t ws_size,
                              hipStream_t stream) {
    const float* x        = (const float*)d_in[0];
    const int*   eidx     = (const int*)d_in[1];
    const float* W_in     = (const float*)d_in[2];
    const float* b_in     = (const float*)d_in[3];
    const float* W_layers = (const float*)d_in[4];
    const float* b_layers = (const float*)d_in[5];
    float* h = (float*)d_out;

    const int* src = eidx;
    const int* dst = eidx + NE;

    // workspace carve-up (~33 MB)
    char* p = (char*)d_ws;
    ushort* mh = (ushort*)p;      p += align_up(sizeof(ushort) * ((size_t)NN + 1) * HD, 256);
    ushort* hb = (ushort*)p;      p += align_up(sizeof(ushort) * (size_t)NN * HD, 256);
    ushort* WT = (ushort*)p;      p += align_up(sizeof(ushort) * 4 * HD * HD, 256);
    float* isq = (float*)p;       p += align_up(sizeof(float) * NN, 256);
    int* deg = (int*)p;           p += align_up(sizeof(int) * NN, 256);
    int* cursor = (int*)p;        p += align_up(sizeof(int) * NN, 256);
    int* rowptr = (int*)p;        p += align_up(sizeof(int) * (NN + 1), 256);
    int* partial = (int*)p;       p += align_up(sizeof(int) * (NBLK + 1), 256);
    int* csrb = (int*)p;          p += align_up(sizeof(int) * NE, 256);

    // K1: zero deg + transpose/convert all W
    init_k<<<NBLK + TW_BLKS, 256, 0, stream>>>(deg, W_in, W_layers, WT);
    // K2: h = x @ W_in + b_in (hb = bf16(h))  ||  XCD-local count_deg
    gemm0_deg_k<<<GB + FIL_BLKS, 256, 0, stream>>>(x, WT, b_in, h, hb, dst, deg);
    // K3/K4: scan deg -> rowptr; cursor/isq/pad
    scan_partial_k<<<NBLK, 1024, 0, stream>>>(deg, rowptr, partial);
    add_off_isq_k<<<NBLK, 1024, 0, stream>>>(deg, rowptr, partial, cursor, isq, mh);
    // K5: mh = bf16((hb @ W_0) * isq)  ||  XCD-local csr_fill
    gemm1_csr_k<<<GB + FIL_BLKS, 256, 0, stream>>>(hb, WT + (size_t)HD * HD, isq, mh,
                                                   src, dst, cursor, csrb);

    for (int l = 0; l < NL; ++l) {
        if (l > 0) {
            // mh = bf16((hb @ W_l) * isq)
            gemm_mfma_k<<<GB, 256, 0, stream>>>(hb, WT + (size_t)(l + 1) * HD * HD,
                                                isq, mh);
        }
        // h = gelu(isq*(sum mh[src] + mh[v]) + b_l) + h ; hb = bf16(h) except last
        if (l < NL - 1)
            aggregate_k<1><<<(NN + 3) / 4, 256, 0, stream>>>(mh, rowptr, csrb, isq,
                                                             b_layers + (size_t)l * HD, h, hb);
        else
            aggregate_k<0><<<(NN + 3) / 4, 256, 0, stream>>>(mh, rowptr, csrb, isq,
                                                             b_layers + (size_t)l * HD, h, hb);
    }
}

// Round 16
// 195.786 us; speedup vs baseline: 1.1058x; 1.0459x over previous
//
#include <hip/hip_runtime.h>
#include <hip/hip_bf16.h>
#include <math.h>

#define NN 50000
#define NE 600000
#define HD 128
#define NL 3
#define NBLK 49        // ceil(NN/1024)
#define TW_BLKS 64     // 64*256*4 = 65536 = 4*128*128
#define GB 782         // gemm blocks (BM=64)
#define NCHUNK 512     // edge chunks per residue
#define CHK 1172       // ceil(NE/NCHUNK)
#define FIL_BLKS (8 * NCHUNK)  // 4096 partner blocks (8 residues x 512 chunks)
#define DRANGE 6250    // NN/8 dst's per XCD residue
#define ZERO_OFF (NN << 8)   // byte offset of zero pad row mh[NN]

typedef __attribute__((ext_vector_type(8))) short short8;
typedef __attribute__((ext_vector_type(4))) float f32x4;

__device__ __forceinline__ ushort f2bf(float v) {
    union { float f; unsigned u; } c; c.f = v;
    unsigned u = c.u;
    u = (u + 0x7fffu + ((u >> 16) & 1u)) >> 16;
    return (ushort)u;
}
__device__ __forceinline__ float u2f(uint u) {
    union { uint u; float f; } c; c.u = u; return c.f;
}

// ---------- K1: zero deg (blocks [0,NBLK)) + W transpose (blocks rest) -------
__global__ __launch_bounds__(256) void init_k(int* __restrict__ deg,
                                              const float* __restrict__ W_in,
                                              const float* __restrict__ W_layers,
                                              ushort* __restrict__ WT) {
    int b = blockIdx.x;
    if (b < NBLK) {
        int base = b * 1024 + threadIdx.x * 4;
        if (base + 4 <= NN) {
            *(int4*)(deg + base) = int4{0, 0, 0, 0};
        } else {
            for (int u = 0; u < 4; ++u) if (base + u < NN) deg[base + u] = 0;
        }
    } else {
        int tloc = (b - NBLK) * 256 + threadIdx.x; // 0..16383
        #pragma unroll
        for (int q = 0; q < 4; ++q) {
            int idx = tloc + q * 16384;
            int m = idx >> 14;
            int c = (idx >> 7) & 127;
            int k = idx & 127;
            const float* W = (m == 0) ? W_in : (W_layers + (size_t)(m - 1) * HD * HD);
            WT[idx] = f2bf(W[k * HD + c]);
        }
    }
}

// ---------- scan phase 1: block-local exclusive scan + block totals ----------
__global__ __launch_bounds__(1024) void scan_partial_k(const int* __restrict__ deg,
                                                       int* __restrict__ rowptr,
                                                       int* __restrict__ partial) {
    __shared__ int wsum[16];
    int tid = threadIdx.x;
    int lane = tid & 63, w = tid >> 6;
    int v = blockIdx.x * 1024 + tid;
    int x = (v < NN) ? deg[v] : 0;
    int s = x;
    #pragma unroll
    for (int off = 1; off < 64; off <<= 1) {
        int t = __shfl_up(s, off);
        if (lane >= off) s += t;
    }
    if (lane == 63) wsum[w] = s;
    __syncthreads();
    if (w == 0) {
        int t = (lane < 16) ? wsum[lane] : 0;
        #pragma unroll
        for (int off = 1; off < 16; off <<= 1) {
            int u = __shfl_up(t, off);
            if (lane >= off) t += u;
        }
        if (lane < 16) wsum[lane] = t;
    }
    __syncthreads();
    int incl = s + ((w > 0) ? wsum[w - 1] : 0);
    if (v < NN) rowptr[v] = incl - x;
    if (tid == 1023) partial[blockIdx.x] = incl;
}

// ---------- scan phase 2 (fused): redundant 49-scan per block + finalize -----
__global__ __launch_bounds__(1024) void add_off_isq_k(const int* __restrict__ deg,
                                                      int* __restrict__ rowptr,
                                                      const int* __restrict__ partial,
                                                      int* __restrict__ cursor,
                                                      float* __restrict__ isq,
                                                      ushort* __restrict__ mh) {
    __shared__ int spart[NBLK + 1];
    int tid = threadIdx.x;
    if (tid < 64) {
        int xval = (tid < NBLK) ? partial[tid] : 0;
        int s = xval;
        #pragma unroll
        for (int off = 1; off < 64; off <<= 1) {
            int t = __shfl_up(s, off);
            if (tid >= off) s += t;
        }
        if (tid < NBLK) spart[tid] = s - xval;   // exclusive
        if (tid == NBLK - 1) spart[NBLK] = s;    // grand total
    }
    __syncthreads();
    int v = blockIdx.x * 1024 + tid;
    if (v < NN) {
        int rv = rowptr[v] + spart[blockIdx.x];
        rowptr[v] = rv;
        cursor[v] = rv;
        isq[v] = rsqrtf((float)(deg[v] + 1));
    }
    if (blockIdx.x == 0 && tid == 0) rowptr[NN] = spart[NBLK];
    // zero the pad row mh[NN] (256 B)
    if (blockIdx.x == 0 && tid < 64)
        ((uint*)(mh + (size_t)NN * HD))[tid] = 0u;
}

// ---------------- GEMM body: out = A[nrows,128] @ W[128,128] -----------------
// BM=64, 4 waves, each wave owns 16 rows x 128 cols.
// MODE 0: A f32 (x).  hb[r][c] = bf16(acc + bias[c])
// MODE 1: A bf16 (hb). mh[r][c] = bf16(acc * isq[r])
template<int MODE>
__device__ __forceinline__ void gemm_body(int bid, const void* __restrict__ Av,
                                          const ushort* __restrict__ WT,
                                          const float* __restrict__ bs,
                                          ushort* __restrict__ out_b16,
                                          int nrows, ushort* swT) {
    int tid = threadIdx.x;
    #pragma unroll
    for (int i = 0; i < 8; ++i) {
        int chunk = tid + i * 256;
        int lin = chunk << 4;
        int n = lin >> 8;
        int swz = lin ^ ((n & 7) << 4);
        *(float4*)((char*)swT + swz) = *(const float4*)(WT + chunk * 8);
    }
    __syncthreads();

    int w = tid >> 6, l = tid & 63;
    int ar = l & 15, ag = l >> 4;
    int r0 = bid * 64 + w * 16;
    int arow = r0 + ar;
    bool arow_ok = arow < nrows;

    short8 afr[4];
    #pragma unroll
    for (int ks = 0; ks < 4; ++ks) {
        if (MODE == 0) {
            short8 fr = {0,0,0,0,0,0,0,0};
            if (arow_ok) {
                const float* Af = (const float*)Av;
                float4 p0 = *(const float4*)(Af + (size_t)arow * HD + ks * 32 + ag * 8);
                float4 p1 = *(const float4*)(Af + (size_t)arow * HD + ks * 32 + ag * 8 + 4);
                fr[0] = (short)f2bf(p0.x); fr[1] = (short)f2bf(p0.y);
                fr[2] = (short)f2bf(p0.z); fr[3] = (short)f2bf(p0.w);
                fr[4] = (short)f2bf(p1.x); fr[5] = (short)f2bf(p1.y);
                fr[6] = (short)f2bf(p1.z); fr[7] = (short)f2bf(p1.w);
            }
            afr[ks] = fr;
        } else {
            const ushort* Ab = (const ushort*)Av;
            afr[ks] = arow_ok ? *(const short8*)(Ab + (size_t)arow * HD + ks * 32 + ag * 8)
                              : short8{0,0,0,0,0,0,0,0};
        }
    }

    f32x4 acc[8];
    #pragma unroll
    for (int t = 0; t < 8; ++t) acc[t] = f32x4{0.f, 0.f, 0.f, 0.f};

    #pragma unroll
    for (int ks = 0; ks < 4; ++ks) {
        #pragma unroll
        for (int t = 0; t < 8; ++t) {
            int n = t * 16 + ar;
            int lin = (n << 8) + ks * 64 + ag * 16;
            int swz = lin ^ ((ar & 7) << 4);
            short8 b = *(const short8*)((const char*)swT + swz);
            acc[t] = __builtin_amdgcn_mfma_f32_16x16x32_bf16(afr[ks], b, acc[t], 0, 0, 0);
        }
    }

    #pragma unroll
    for (int q = 0; q < 4; ++q) {
        int row = r0 + ag * 4 + q;
        if (row >= nrows) continue;
        if (MODE == 0) {
            #pragma unroll
            for (int t = 0; t < 8; ++t) {
                int col = t * 16 + ar;
                out_b16[(size_t)row * HD + col] = f2bf(acc[t][q] + bs[col]);
            }
        } else {
            float s = bs[row];
            #pragma unroll
            for (int t = 0; t < 8; ++t) {
                int col = t * 16 + ar;
                out_b16[(size_t)row * HD + col] = f2bf(acc[t][q] * s);
            }
        }
    }
}

// ---------- K2: gemm0 (blocks [0,GB)) + XCD-local count_deg (rest) -----------
__global__ __launch_bounds__(256) void gemm0_deg_k(const float* __restrict__ x,
                                                   const ushort* __restrict__ WT,
                                                   const float* __restrict__ b_in,
                                                   ushort* __restrict__ hb,
                                                   const int* __restrict__ dst,
                                                   int* __restrict__ deg) {
    __shared__ ushort swT[HD * HD];
    int b = blockIdx.x;
    if (b < GB) {
        gemm_body<0>(b, x, WT, b_in, hb, NN, swT);
        return;
    }
    int r = b & 7;
    int j = (b - GB) >> 3;
    int dlo = r * DRANGE, dhi = dlo + DRANGE;
    int base = j * CHK;
    int end = min(base + CHK, NE);
    for (int e = base + (int)threadIdx.x; e < end; e += 256) {
        int d = dst[e];
        if (d >= dlo && d < dhi) atomicAdd(&deg[d], 1);
    }
}

// ---------- K5: gemm1 (blocks [0,GB)) + XCD-local csr_fill (rest) ------------
__global__ __launch_bounds__(256) void gemm1_csr_k(const ushort* __restrict__ hb,
                                                   const ushort* __restrict__ WT1,
                                                   const float* __restrict__ isq,
                                                   ushort* __restrict__ mh,
                                                   const int* __restrict__ src,
                                                   const int* __restrict__ dst,
                                                   int* __restrict__ cursor,
                                                   int* __restrict__ csrb) {
    __shared__ ushort swT[HD * HD];
    int b = blockIdx.x;
    if (b < GB) {
        gemm_body<1>(b, hb, WT1, isq, mh, NN, swT);
        return;
    }
    int r = b & 7;
    int j = (b - GB) >> 3;
    int dlo = r * DRANGE, dhi = dlo + DRANGE;
    int base = j * CHK;
    int end = min(base + CHK, NE);
    for (int e = base + (int)threadIdx.x; e < end; e += 256) {
        int d = dst[e];
        if (d >= dlo && d < dhi) {
            int pos = atomicAdd(&cursor[d], 1);   // L2-local round trip
            csrb[pos] = src[e] << 8;              // row byte offset (HD*2 = 256 B)
        }
    }
}

// ---------- plain gemm kernel for layers 1,2 ---------------------------------
__global__ __launch_bounds__(256) void gemm_mfma_k(const ushort* __restrict__ A,
                                                   const ushort* __restrict__ WT,
                                                   const float* __restrict__ isq,
                                                   ushort* __restrict__ mh) {
    __shared__ ushort swT[HD * HD];
    gemm_body<1>(blockIdx.x, A, WT, isq, mh, NN, swT);
}

// ------- aggregation: one wave/node, flat-16 unpredicated batches (depth-1) --
// residual kept in bf16 hb across layers; final layer writes f32 d_out.
// LAST=0: hb[v] = bf16( gelu(isq*(sum+self)+b) + hb[v] )
// LAST=1: h[v]  =       gelu(isq*(sum+self)+b) + hb[v]   (f32 out)
template<int LAST>
__global__ __launch_bounds__(256) void aggregate_k(const ushort* __restrict__ mh,
                                                   const int* __restrict__ rowptr,
                                                   const int* __restrict__ csrb,
                                                   const float* __restrict__ isq,
                                                   const float* __restrict__ bias,
                                                   float* __restrict__ h,
                                                   ushort* __restrict__ hb) {
    int gw = (int)((blockIdx.x * blockDim.x + threadIdx.x) >> 6);
    int lane = threadIdx.x & 63;
    if (gw >= NN) return;
    int v = gw;
    int2 rp = *(const int2*)&rowptr[v];
    const char* mh_lane = (const char*)mh + lane * 4; // this lane's 2 channels

    // self-loop init
    uint sp = *(const uint*)(mh_lane + ((size_t)v << 8));
    float accx = u2f(sp << 16), accy = u2f(sp & 0xffff0000u);

    for (int i = rp.x; i < rp.y; i += 64) {
        int offs = (i + lane < rp.y) ? csrb[i + lane] : ZERO_OFF;
        int cnt = min(64, rp.y - i);
        int nb = (cnt + 15) >> 4;          // 1..4 batches of 16 (pads -> zero row)
        for (int b = 0; b < nb; ++b) {
            int jb = b << 4;
            int o0  = __shfl(offs, jb);
            int o1  = __shfl(offs, jb + 1);
            int o2  = __shfl(offs, jb + 2);
            int o3  = __shfl(offs, jb + 3);
            int o4  = __shfl(offs, jb + 4);
            int o5  = __shfl(offs, jb + 5);
            int o6  = __shfl(offs, jb + 6);
            int o7  = __shfl(offs, jb + 7);
            int o8  = __shfl(offs, jb + 8);
            int o9  = __shfl(offs, jb + 9);
            int o10 = __shfl(offs, jb + 10);
            int o11 = __shfl(offs, jb + 11);
            int o12 = __shfl(offs, jb + 12);
            int o13 = __shfl(offs, jb + 13);
            int o14 = __shfl(offs, jb + 14);
            int o15 = __shfl(offs, jb + 15);
            uint p0  = *(const uint*)(mh_lane + o0);
            uint p1  = *(const uint*)(mh_lane + o1);
            uint p2  = *(const uint*)(mh_lane + o2);
            uint p3  = *(const uint*)(mh_lane + o3);
            uint p4  = *(const uint*)(mh_lane + o4);
            uint p5  = *(const uint*)(mh_lane + o5);
            uint p6  = *(const uint*)(mh_lane + o6);
            uint p7  = *(const uint*)(mh_lane + o7);
            uint p8  = *(const uint*)(mh_lane + o8);
            uint p9  = *(const uint*)(mh_lane + o9);
            uint p10 = *(const uint*)(mh_lane + o10);
            uint p11 = *(const uint*)(mh_lane + o11);
            uint p12 = *(const uint*)(mh_lane + o12);
            uint p13 = *(const uint*)(mh_lane + o13);
            uint p14 = *(const uint*)(mh_lane + o14);
            uint p15 = *(const uint*)(mh_lane + o15);
            accx += u2f(p0 << 16);  accy += u2f(p0 & 0xffff0000u);
            accx += u2f(p1 << 16);  accy += u2f(p1 & 0xffff0000u);
            accx += u2f(p2 << 16);  accy += u2f(p2 & 0xffff0000u);
            accx += u2f(p3 << 16);  accy += u2f(p3 & 0xffff0000u);
            accx += u2f(p4 << 16);  accy += u2f(p4 & 0xffff0000u);
            accx += u2f(p5 << 16);  accy += u2f(p5 & 0xffff0000u);
            accx += u2f(p6 << 16);  accy += u2f(p6 & 0xffff0000u);
            accx += u2f(p7 << 16);  accy += u2f(p7 & 0xffff0000u);
            accx += u2f(p8 << 16);  accy += u2f(p8 & 0xffff0000u);
            accx += u2f(p9 << 16);  accy += u2f(p9 & 0xffff0000u);
            accx += u2f(p10 << 16); accy += u2f(p10 & 0xffff0000u);
            accx += u2f(p11 << 16); accy += u2f(p11 & 0xffff0000u);
            accx += u2f(p12 << 16); accy += u2f(p12 & 0xffff0000u);
            accx += u2f(p13 << 16); accy += u2f(p13 & 0xffff0000u);
            accx += u2f(p14 << 16); accy += u2f(p14 & 0xffff0000u);
            accx += u2f(p15 << 16); accy += u2f(p15 & 0xffff0000u);
        }
    }

    float is = isq[v];
    float2 b = *(const float2*)&bias[lane * 2];
    float ax = accx * is + b.x;
    float ay = accy * is + b.y;
    float gx = 0.5f * ax * (1.f + erff(ax * 0.70710678118654752f));
    float gy = 0.5f * ay * (1.f + erff(ay * 0.70710678118654752f));
    // residual from bf16 hb
    uint* hbp = (uint*)((char*)hb + ((size_t)v << 8) + lane * 4);
    uint hp0 = *hbp;
    float hx = u2f(hp0 << 16) + gx;
    float hy = u2f(hp0 & 0xffff0000u) + gy;
    if (LAST) {
        *(float2*)(h + (size_t)v * HD + lane * 2) = float2{hx, hy};
    } else {
        *hbp = ((uint)f2bf(hx)) | (((uint)f2bf(hy)) << 16);
    }
}

// ---------------- launch ----------------

static inline size_t align_up(size_t x, size_t a) { return (x + a - 1) & ~(a - 1); }

extern "C" void kernel_launch(void* const* d_in, const int* in_sizes, int n_in,
                              void* d_out, int out_size, void* d_ws, size_t ws_size,
                              hipStream_t stream) {
    const float* x        = (const float*)d_in[0];
    const int*   eidx     = (const int*)d_in[1];
    const float* W_in     = (const float*)d_in[2];
    const float* b_in     = (const float*)d_in[3];
    const float* W_layers = (const float*)d_in[4];
    const float* b_layers = (const float*)d_in[5];
    float* h = (float*)d_out;

    const int* src = eidx;
    const int* dst = eidx + NE;

    // workspace carve-up (~33 MB)
    char* p = (char*)d_ws;
    ushort* mh = (ushort*)p;      p += align_up(sizeof(ushort) * ((size_t)NN + 1) * HD, 256);
    ushort* hb = (ushort*)p;      p += align_up(sizeof(ushort) * (size_t)NN * HD, 256);
    ushort* WT = (ushort*)p;      p += align_up(sizeof(ushort) * 4 * HD * HD, 256);
    float* isq = (float*)p;       p += align_up(sizeof(float) * NN, 256);
    int* deg = (int*)p;           p += align_up(sizeof(int) * NN, 256);
    int* cursor = (int*)p;        p += align_up(sizeof(int) * NN, 256);
    int* rowptr = (int*)p;        p += align_up(sizeof(int) * (NN + 1), 256);
    int* partial = (int*)p;       p += align_up(sizeof(int) * (NBLK + 1), 256);
    int* csrb = (int*)p;          p += align_up(sizeof(int) * NE, 256);

    // K1: zero deg + transpose/convert all W
    init_k<<<NBLK + TW_BLKS, 256, 0, stream>>>(deg, W_in, W_layers, WT);
    // K2: hb = bf16(x @ W_in + b_in)  ||  XCD-local count_deg
    gemm0_deg_k<<<GB + FIL_BLKS, 256, 0, stream>>>(x, WT, b_in, hb, dst, deg);
    // K3/K4: scan deg -> rowptr; cursor/isq/pad
    scan_partial_k<<<NBLK, 1024, 0, stream>>>(deg, rowptr, partial);
    add_off_isq_k<<<NBLK, 1024, 0, stream>>>(deg, rowptr, partial, cursor, isq, mh);
    // K5: mh = bf16((hb @ W_0) * isq)  ||  XCD-local csr_fill
    gemm1_csr_k<<<GB + FIL_BLKS, 256, 0, stream>>>(hb, WT + (size_t)HD * HD, isq, mh,
                                                   src, dst, cursor, csrb);

    for (int l = 0; l < NL; ++l) {
        if (l > 0) {
            // mh = bf16((hb @ W_l) * isq)
            gemm_mfma_k<<<GB, 256, 0, stream>>>(hb, WT + (size_t)(l + 1) * HD * HD,
                                                isq, mh);
        }
        // hb/h update with residual in bf16; last layer writes f32 d_out
        if (l < NL - 1)
            aggregate_k<0><<<(NN + 3) / 4, 256, 0, stream>>>(mh, rowptr, csrb, isq,
                                                             b_layers + (size_t)l * HD, h, hb);
        else
            aggregate_k<1><<<(NN + 3) / 4, 256, 0, stream>>>(mh, rowptr, csrb, isq,
                                                             b_layers + (size_t)l * HD, h, hb);
    }
}

// Round 17
// 172.918 us; speedup vs baseline: 1.2520x; 1.1323x over previous
//
#include <hip/hip_runtime.h>
#include <hip/hip_bf16.h>
#include <math.h>

#define NN 50000
#define NE 600000
#define HD 128
#define NL 3
#define NBLK 49        // ceil(NN/1024)
#define TW_BLKS 64     // 64*256*4 = 65536 = 4*128*128
#define GB 782         // gemm blocks (BM=64)
#define NCHUNK 512     // edge chunks per residue
#define CHK 1172       // ceil(NE/NCHUNK)
#define FIL_BLKS (8 * NCHUNK)  // 4096 partner blocks (8 residues x 512 chunks)
#define DRANGE 6250    // NN/8 dst's per XCD residue
#define ISQ_BLKS 196   // ceil(NN/256)
#define ELLW 64        // ELL width: P(Poisson(12) > 63) ~ 1e-30
#define ZERO_OFF (NN << 8)   // byte offset of zero pad row mh[NN]

typedef __attribute__((ext_vector_type(8))) short short8;
typedef __attribute__((ext_vector_type(4))) float f32x4;

__device__ __forceinline__ ushort f2bf(float v) {
    union { float f; unsigned u; } c; c.f = v;
    unsigned u = c.u;
    u = (u + 0x7fffu + ((u >> 16) & 1u)) >> 16;
    return (ushort)u;
}
__device__ __forceinline__ float u2f(uint u) {
    union { uint u; float f; } c; c.u = u; return c.f;
}

// ---------- K1: zero cnt + mh pad row (blocks [0,NBLK)) + W transpose --------
__global__ __launch_bounds__(256) void init_k(int* __restrict__ cnt,
                                              const float* __restrict__ W_in,
                                              const float* __restrict__ W_layers,
                                              ushort* __restrict__ WT,
                                              ushort* __restrict__ mh) {
    int b = blockIdx.x;
    if (b < NBLK) {
        int base = b * 1024 + threadIdx.x * 4;
        if (base + 4 <= NN) {
            *(int4*)(cnt + base) = int4{0, 0, 0, 0};
        } else {
            for (int u = 0; u < 4; ++u) if (base + u < NN) cnt[base + u] = 0;
        }
        if (b == 0 && threadIdx.x < 64)  // zero the pad row mh[NN] (256 B)
            ((uint*)(mh + (size_t)NN * HD))[threadIdx.x] = 0u;
    } else {
        int tloc = (b - NBLK) * 256 + threadIdx.x; // 0..16383
        #pragma unroll
        for (int q = 0; q < 4; ++q) {
            int idx = tloc + q * 16384;
            int m = idx >> 14;
            int c = (idx >> 7) & 127;
            int k = idx & 127;
            const float* W = (m == 0) ? W_in : (W_layers + (size_t)(m - 1) * HD * HD);
            WT[idx] = f2bf(W[k * HD + c]);
        }
    }
}

// ---------------- GEMM body: out = A[nrows,128] @ W[128,128] -----------------
// BM=64, 4 waves, each wave owns 16 rows x 128 cols.
// MODE 0: A f32 (x).  hb[r][c] = bf16(acc + bias[c])
// MODE 1: A bf16 (hb). mh[r][c] = bf16(acc * isq[r])
template<int MODE>
__device__ __forceinline__ void gemm_body(int bid, const void* __restrict__ Av,
                                          const ushort* __restrict__ WT,
                                          const float* __restrict__ bs,
                                          ushort* __restrict__ out_b16,
                                          int nrows, ushort* swT) {
    int tid = threadIdx.x;
    #pragma unroll
    for (int i = 0; i < 8; ++i) {
        int chunk = tid + i * 256;
        int lin = chunk << 4;
        int n = lin >> 8;
        int swz = lin ^ ((n & 7) << 4);
        *(float4*)((char*)swT + swz) = *(const float4*)(WT + chunk * 8);
    }
    __syncthreads();

    int w = tid >> 6, l = tid & 63;
    int ar = l & 15, ag = l >> 4;
    int r0 = bid * 64 + w * 16;
    int arow = r0 + ar;
    bool arow_ok = arow < nrows;

    short8 afr[4];
    #pragma unroll
    for (int ks = 0; ks < 4; ++ks) {
        if (MODE == 0) {
            short8 fr = {0,0,0,0,0,0,0,0};
            if (arow_ok) {
                const float* Af = (const float*)Av;
                float4 p0 = *(const float4*)(Af + (size_t)arow * HD + ks * 32 + ag * 8);
                float4 p1 = *(const float4*)(Af + (size_t)arow * HD + ks * 32 + ag * 8 + 4);
                fr[0] = (short)f2bf(p0.x); fr[1] = (short)f2bf(p0.y);
                fr[2] = (short)f2bf(p0.z); fr[3] = (short)f2bf(p0.w);
                fr[4] = (short)f2bf(p1.x); fr[5] = (short)f2bf(p1.y);
                fr[6] = (short)f2bf(p1.z); fr[7] = (short)f2bf(p1.w);
            }
            afr[ks] = fr;
        } else {
            const ushort* Ab = (const ushort*)Av;
            afr[ks] = arow_ok ? *(const short8*)(Ab + (size_t)arow * HD + ks * 32 + ag * 8)
                              : short8{0,0,0,0,0,0,0,0};
        }
    }

    f32x4 acc[8];
    #pragma unroll
    for (int t = 0; t < 8; ++t) acc[t] = f32x4{0.f, 0.f, 0.f, 0.f};

    #pragma unroll
    for (int ks = 0; ks < 4; ++ks) {
        #pragma unroll
        for (int t = 0; t < 8; ++t) {
            int n = t * 16 + ar;
            int lin = (n << 8) + ks * 64 + ag * 16;
            int swz = lin ^ ((ar & 7) << 4);
            short8 b = *(const short8*)((const char*)swT + swz);
            acc[t] = __builtin_amdgcn_mfma_f32_16x16x32_bf16(afr[ks], b, acc[t], 0, 0, 0);
        }
    }

    #pragma unroll
    for (int q = 0; q < 4; ++q) {
        int row = r0 + ag * 4 + q;
        if (row >= nrows) continue;
        if (MODE == 0) {
            #pragma unroll
            for (int t = 0; t < 8; ++t) {
                int col = t * 16 + ar;
                out_b16[(size_t)row * HD + col] = f2bf(acc[t][q] + bs[col]);
            }
        } else {
            float s = bs[row];
            #pragma unroll
            for (int t = 0; t < 8; ++t) {
                int col = t * 16 + ar;
                out_b16[(size_t)row * HD + col] = f2bf(acc[t][q] * s);
            }
        }
    }
}

// ---------- K2: gemm0 (blocks [0,GB)) + XCD-local ELL build (rest) -----------
// Single atomic pass builds BOTH degree count and adjacency (ELL, width 64).
__global__ __launch_bounds__(256) void gemm0_ell_k(const float* __restrict__ x,
                                                   const ushort* __restrict__ WT,
                                                   const float* __restrict__ b_in,
                                                   ushort* __restrict__ hb,
                                                   const int* __restrict__ src,
                                                   const int* __restrict__ dst,
                                                   int* __restrict__ cnt,
                                                   int* __restrict__ ell) {
    __shared__ ushort swT[HD * HD];
    int b = blockIdx.x;
    if (b < GB) {
        gemm_body<0>(b, x, WT, b_in, hb, NN, swT);
        return;
    }
    int r = b & 7;
    int j = (b - GB) >> 3;
    int dlo = r * DRANGE, dhi = dlo + DRANGE;
    int base = j * CHK;
    int end = min(base + CHK, NE);
    for (int e = base + (int)threadIdx.x; e < end; e += 256) {
        int d = dst[e];
        if (d >= dlo && d < dhi) {
            int pos = atomicAdd(&cnt[d], 1);     // L2-local
            if (pos < ELLW) ell[(d << 6) + pos] = src[e] << 8;
        }
    }
}

// ---------- K3: gemm1 (blocks [0,GB)) + isq (rest) ---------------------------
__global__ __launch_bounds__(256) void gemm1_isq_k(const ushort* __restrict__ hb,
                                                   const ushort* __restrict__ WT1,
                                                   const float* __restrict__ dummy_isq,
                                                   ushort* __restrict__ mh,
                                                   const int* __restrict__ cnt,
                                                   float* __restrict__ isq) {
    __shared__ ushort swT[HD * HD];
    int b = blockIdx.x;
    if (b < GB) {
        gemm_body<1>(b, hb, WT1, dummy_isq, mh, NN, swT);
        return;
    }
    int v = (b - GB) * 256 + threadIdx.x;
    if (v < NN) isq[v] = rsqrtf((float)(cnt[v] + 1));
}

// NOTE: gemm1 (layer 0's transform) needs isq in its epilogue, but isq is
// computed in the SAME kernel. Resolve by ordering: layer-0 GEMM must run
// AFTER isq. So K3 computes isq only (partner blocks) alongside... see launch:
// we instead fuse isq with a plain-gemm that does NOT need isq? gemm MODE1
// epilogue multiplies by isq[row] -> must come after isq. Therefore K3 is
// isq-only (tiny), and layer-0 gemm runs after it (plain). To keep dispatch
// count low, K3's partner work rides with NOTHING; instead we fuse isq into
// the FIRST plain gemm? Same problem. So: isq is a standalone tiny kernel.

// ---------- plain gemm kernel for all layer transforms -----------------------
__global__ __launch_bounds__(256) void gemm_mfma_k(const ushort* __restrict__ A,
                                                   const ushort* __restrict__ WT,
                                                   const float* __restrict__ isq,
                                                   ushort* __restrict__ mh) {
    __shared__ ushort swT[HD * HD];
    gemm_body<1>(blockIdx.x, A, WT, isq, mh, NN, swT);
}

__global__ __launch_bounds__(256) void isq_k(const int* __restrict__ cnt,
                                             float* __restrict__ isq) {
    int v = blockIdx.x * 256 + threadIdx.x;
    if (v < NN) isq[v] = rsqrtf((float)(cnt[v] + 1));
}

// ------- aggregation: one wave/node, ELL direct, flat-16 batches (depth-1) ---
// residual kept in bf16 hb across layers; final layer writes f32 d_out.
template<int LAST>
__global__ __launch_bounds__(256) void aggregate_k(const ushort* __restrict__ mh,
                                                   const int* __restrict__ cntp,
                                                   const int* __restrict__ ell,
                                                   const float* __restrict__ isq,
                                                   const float* __restrict__ bias,
                                                   float* __restrict__ h,
                                                   ushort* __restrict__ hb) {
    int gw = (int)((blockIdx.x * blockDim.x + threadIdx.x) >> 6);
    int lane = threadIdx.x & 63;
    if (gw >= NN) return;
    int v = gw;
    int cnt = min(cntp[v], ELLW);
    const char* mh_lane = (const char*)mh + lane * 4; // this lane's 2 channels

    // self-loop init
    uint sp = *(const uint*)(mh_lane + ((size_t)v << 8));
    float accx = u2f(sp << 16), accy = u2f(sp & 0xffff0000u);

    int offs = (lane < cnt) ? ell[(v << 6) + lane] : ZERO_OFF;
    int nb = (cnt + 15) >> 4;              // 0..4 batches of 16 (pads -> zero row)
    for (int b = 0; b < nb; ++b) {
        int jb = b << 4;
        int o0  = __shfl(offs, jb);
        int o1  = __shfl(offs, jb + 1);
        int o2  = __shfl(offs, jb + 2);
        int o3  = __shfl(offs, jb + 3);
        int o4  = __shfl(offs, jb + 4);
        int o5  = __shfl(offs, jb + 5);
        int o6  = __shfl(offs, jb + 6);
        int o7  = __shfl(offs, jb + 7);
        int o8  = __shfl(offs, jb + 8);
        int o9  = __shfl(offs, jb + 9);
        int o10 = __shfl(offs, jb + 10);
        int o11 = __shfl(offs, jb + 11);
        int o12 = __shfl(offs, jb + 12);
        int o13 = __shfl(offs, jb + 13);
        int o14 = __shfl(offs, jb + 14);
        int o15 = __shfl(offs, jb + 15);
        uint p0  = *(const uint*)(mh_lane + o0);
        uint p1  = *(const uint*)(mh_lane + o1);
        uint p2  = *(const uint*)(mh_lane + o2);
        uint p3  = *(const uint*)(mh_lane + o3);
        uint p4  = *(const uint*)(mh_lane + o4);
        uint p5  = *(const uint*)(mh_lane + o5);
        uint p6  = *(const uint*)(mh_lane + o6);
        uint p7  = *(const uint*)(mh_lane + o7);
        uint p8  = *(const uint*)(mh_lane + o8);
        uint p9  = *(const uint*)(mh_lane + o9);
        uint p10 = *(const uint*)(mh_lane + o10);
        uint p11 = *(const uint*)(mh_lane + o11);
        uint p12 = *(const uint*)(mh_lane + o12);
        uint p13 = *(const uint*)(mh_lane + o13);
        uint p14 = *(const uint*)(mh_lane + o14);
        uint p15 = *(const uint*)(mh_lane + o15);
        accx += u2f(p0 << 16);  accy += u2f(p0 & 0xffff0000u);
        accx += u2f(p1 << 16);  accy += u2f(p1 & 0xffff0000u);
        accx += u2f(p2 << 16);  accy += u2f(p2 & 0xffff0000u);
        accx += u2f(p3 << 16);  accy += u2f(p3 & 0xffff0000u);
        accx += u2f(p4 << 16);  accy += u2f(p4 & 0xffff0000u);
        accx += u2f(p5 << 16);  accy += u2f(p5 & 0xffff0000u);
        accx += u2f(p6 << 16);  accy += u2f(p6 & 0xffff0000u);
        accx += u2f(p7 << 16);  accy += u2f(p7 & 0xffff0000u);
        accx += u2f(p8 << 16);  accy += u2f(p8 & 0xffff0000u);
        accx += u2f(p9 << 16);  accy += u2f(p9 & 0xffff0000u);
        accx += u2f(p10 << 16); accy += u2f(p10 & 0xffff0000u);
        accx += u2f(p11 << 16); accy += u2f(p11 & 0xffff0000u);
        accx += u2f(p12 << 16); accy += u2f(p12 & 0xffff0000u);
        accx += u2f(p13 << 16); accy += u2f(p13 & 0xffff0000u);
        accx += u2f(p14 << 16); accy += u2f(p14 & 0xffff0000u);
        accx += u2f(p15 << 16); accy += u2f(p15 & 0xffff0000u);
    }

    float is = isq[v];
    float2 b = *(const float2*)&bias[lane * 2];
    float ax = accx * is + b.x;
    float ay = accy * is + b.y;
    float gx = 0.5f * ax * (1.f + erff(ax * 0.70710678118654752f));
    float gy = 0.5f * ay * (1.f + erff(ay * 0.70710678118654752f));
    uint* hbp = (uint*)((char*)hb + ((size_t)v << 8) + lane * 4);
    uint hp0 = *hbp;
    float hx = u2f(hp0 << 16) + gx;
    float hy = u2f(hp0 & 0xffff0000u) + gy;
    if (LAST) {
        *(float2*)(h + (size_t)v * HD + lane * 2) = float2{hx, hy};
    } else {
        *hbp = ((uint)f2bf(hx)) | (((uint)f2bf(hy)) << 16);
    }
}

// ---------------- launch ----------------

static inline size_t align_up(size_t x, size_t a) { return (x + a - 1) & ~(a - 1); }

extern "C" void kernel_launch(void* const* d_in, const int* in_sizes, int n_in,
                              void* d_out, int out_size, void* d_ws, size_t ws_size,
                              hipStream_t stream) {
    const float* x        = (const float*)d_in[0];
    const int*   eidx     = (const int*)d_in[1];
    const float* W_in     = (const float*)d_in[2];
    const float* b_in     = (const float*)d_in[3];
    const float* W_layers = (const float*)d_in[4];
    const float* b_layers = (const float*)d_in[5];
    float* h = (float*)d_out;

    const int* src = eidx;
    const int* dst = eidx + NE;

    // workspace carve-up (~40 MB)
    char* p = (char*)d_ws;
    ushort* mh = (ushort*)p;      p += align_up(sizeof(ushort) * ((size_t)NN + 1) * HD, 256);
    ushort* hb = (ushort*)p;      p += align_up(sizeof(ushort) * (size_t)NN * HD, 256);
    ushort* WT = (ushort*)p;      p += align_up(sizeof(ushort) * 4 * HD * HD, 256);
    float* isq = (float*)p;       p += align_up(sizeof(float) * NN, 256);
    int* cnt = (int*)p;           p += align_up(sizeof(int) * NN, 256);
    int* ell = (int*)p;           p += align_up(sizeof(int) * (size_t)NN * ELLW, 256);

    // K1: zero cnt + mh pad row + transpose/convert all W
    init_k<<<NBLK + TW_BLKS, 256, 0, stream>>>(cnt, W_in, W_layers, WT, mh);
    // K2: hb = bf16(x @ W_in + b_in)  ||  XCD-local ELL build (count+fill, 1 pass)
    gemm0_ell_k<<<GB + FIL_BLKS, 256, 0, stream>>>(x, WT, b_in, hb, src, dst, cnt, ell);
    // K3: isq from cnt (tiny)
    isq_k<<<ISQ_BLKS, 256, 0, stream>>>(cnt, isq);

    for (int l = 0; l < NL; ++l) {
        // mh = bf16((hb @ W_l) * isq)
        gemm_mfma_k<<<GB, 256, 0, stream>>>(hb, WT + (size_t)(l + 1) * HD * HD,
                                            isq, mh);
        // hb/h update with residual in bf16; last layer writes f32 d_out
        if (l < NL - 1)
            aggregate_k<0><<<(NN + 3) / 4, 256, 0, stream>>>(mh, cnt, ell, isq,
                                                             b_layers + (size_t)l * HD, h, hb);
        else
            aggregate_k<1><<<(NN + 3) / 4, 256, 0, stream>>>(mh, cnt, ell, isq,
                                                             b_layers + (size_t)l * HD, h, hb);
    }
}